// Round 1
// baseline (529.890 us; speedup 1.0000x reference)
//
#include <hip/hip_runtime.h>
#include <hip/hip_bf16.h>

typedef __bf16 bf16;
typedef __attribute__((ext_vector_type(2))) __bf16 bf16x2;
typedef __attribute__((ext_vector_type(4))) __bf16 bf16x4;
typedef __attribute__((ext_vector_type(8))) __bf16 bf16x8;
typedef __attribute__((ext_vector_type(4))) float f32x4;

#define NB 2
#define SEQ 1024
#define HIDN 4096
#define NH 32
#define NKV 8
#define DH 128
#define QKV_N 6144
static constexpr float SCALE = 0.08838834764831845f;  // 1/sqrt(128)

__device__ __forceinline__ void async16(const void* g, void* l) {
  __builtin_amdgcn_global_load_lds(
      (const __attribute__((address_space(1))) unsigned int*)g,
      (__attribute__((address_space(3))) unsigned int*)l,
      16, 0, 0);
}

// ---------------- f32 -> bf16 convert (vector) ----------------
__global__ __launch_bounds__(256) void cvt_f32_bf16(const float* __restrict__ src,
                                                    bf16* __restrict__ dst, int n4) {
  int i = blockIdx.x * 256 + threadIdx.x;
  if (i >= n4) return;
  const float4 v = ((const float4*)src)[i];
  bf16x4 o = {(bf16)v.x, (bf16)v.y, (bf16)v.z, (bf16)v.w};
  ((bf16x4*)dst)[i] = o;
}

// ---------------- transpose + convert: dst[N][K] = (bf16)src[K][N] ----------------
__global__ __launch_bounds__(256) void transpose_cvt(const float* __restrict__ src,
                                                     bf16* __restrict__ dst, int R, int C) {
  __shared__ float tl[32][33];
  const int j0 = blockIdx.x * 32, i0 = blockIdx.y * 32;
  const int tr = threadIdx.x >> 5, tc = threadIdx.x & 31;
#pragma unroll
  for (int p = 0; p < 4; ++p)
    tl[tr + p * 8][tc] = src[(size_t)(i0 + tr + p * 8) * C + j0 + tc];
  __syncthreads();
#pragma unroll
  for (int p = 0; p < 4; ++p)
    dst[(size_t)(j0 + tr + p * 8) * R + i0 + tc] = (bf16)tl[tc][tr + p * 8];
}

// ---------------- bf16 GEMM: C[M][N] = A[M][K] * BT[N][K]^T (m97 structure) ----------------
template <int OUT_BF16>
__global__ __launch_bounds__(256) void gemm_bt(const bf16* __restrict__ A,
                                               const bf16* __restrict__ BT,
                                               void* __restrict__ Cout,
                                               int M, int N, int K) {
  __shared__ bf16 As[128 * 32];
  __shared__ bf16 Bs[128 * 32];
  const int t = threadIdx.x;
  const int lane = t & 63, w = t >> 6;
  const int l16 = lane & 15, lq = lane >> 4;
  const int m0 = blockIdx.y * 128, n0 = blockIdx.x * 128;
  const int wr = (w >> 1) * 64, wc = (w & 1) * 64;
  const int sr = t >> 2;
  const int sc = (t & 3) * 8;
  const bf16* ga0 = A + (size_t)(m0 + sr) * K + sc;
  const bf16* ga1 = A + (size_t)(m0 + sr + 64) * K + sc;
  const bf16* gb0 = BT + (size_t)(n0 + sr) * K + sc;
  const bf16* gb1 = BT + (size_t)(n0 + sr + 64) * K + sc;
  char* lA = (char*)As + t * 16;
  char* lB = (char*)Bs + t * 16;

  f32x4 acc[4][4] = {};

  for (int kt = 0; kt < K; kt += 32) {
    __syncthreads();
    async16(ga0 + kt, lA);
    async16(ga1 + kt, lA + 4096);
    async16(gb0 + kt, lB);
    async16(gb1 + kt, lB + 4096);
    __syncthreads();
    bf16x8 af[4], bfr[4];
#pragma unroll
    for (int mt = 0; mt < 4; ++mt)
      af[mt] = *(const bf16x8*)&As[(wr + mt * 16 + l16) * 32 + lq * 8];
#pragma unroll
    for (int nt = 0; nt < 4; ++nt)
      bfr[nt] = *(const bf16x8*)&Bs[(wc + nt * 16 + l16) * 32 + lq * 8];
#pragma unroll
    for (int nt = 0; nt < 4; ++nt)
#pragma unroll
      for (int mt = 0; mt < 4; ++mt)
        acc[mt][nt] =
            __builtin_amdgcn_mfma_f32_16x16x32_bf16(af[mt], bfr[nt], acc[mt][nt], 0, 0, 0);
  }

#pragma unroll
  for (int mt = 0; mt < 4; ++mt)
#pragma unroll
    for (int nt = 0; nt < 4; ++nt)
#pragma unroll
      for (int r = 0; r < 4; ++r) {
        const int row = m0 + wr + mt * 16 + lq * 4 + r;
        const int col = n0 + wc + nt * 16 + l16;
        const float v = acc[mt][nt][r];
        if (OUT_BF16)
          ((bf16*)Cout)[(size_t)row * N + col] = (bf16)v;
        else
          ((float*)Cout)[(size_t)row * N + col] = v;
      }
}

// ---------------- RoPE + reshape: qkv -> Q[b][h][s][d] (scaled), K[b][kv][s][d], VT[b][kv][d][s] ----------------
__global__ __launch_bounds__(256) void rope_reshape(const bf16* __restrict__ qkv,
                                                    const float* __restrict__ cosp,
                                                    const float* __restrict__ sinp,
                                                    bf16* __restrict__ Qo,
                                                    bf16* __restrict__ Ko,
                                                    bf16* __restrict__ VTo) {
  const int row = blockIdx.x;          // b*SEQ + s
  const int b = row >> 10, s = row & 1023;
  const bf16* src = qkv + (size_t)row * QKV_N;
  for (int p = threadIdx.x; p < QKV_N / 2; p += 256) {
    const int col = p * 2;
    bf16x2 x = *(const bf16x2*)&src[col];
    const float x1 = (float)x.x, x2 = (float)x.y;
    if (col < 4096) {
      const int h = col >> 7, d = col & 127, i = (col & 127) >> 1;
      const float c = cosp[s * 64 + i], sn = sinp[s * 64 + i];
      bf16x2 o = {(bf16)((x1 * c - x2 * sn) * SCALE), (bf16)((x1 * sn + x2 * c) * SCALE)};
      *(bf16x2*)&Qo[((size_t)(b * NH + h) * SEQ + s) * DH + d] = o;
    } else if (col < 5120) {
      const int idx = col - 4096;
      const int kvh = idx >> 7, d = idx & 127, i = (idx & 127) >> 1;
      const float c = cosp[s * 64 + i], sn = sinp[s * 64 + i];
      bf16x2 o = {(bf16)(x1 * c - x2 * sn), (bf16)(x1 * sn + x2 * c)};
      *(bf16x2*)&Ko[((size_t)(b * NKV + kvh) * SEQ + s) * DH + d] = o;
    } else {
      const int idx = col - 5120;
      const int kvh = idx >> 7, d = idx & 127;
      bf16* vbase = VTo + ((size_t)(b * NKV + kvh) * DH + d) * SEQ + s;
      vbase[0] = x.x;
      vbase[SEQ] = x.y;
    }
  }
}

// ---------------- causal GQA flash attention ----------------
// grid: (qt=S/64, h=NH, b=B), block 256 (4 waves, each wave = 16 q-rows)
__global__ __launch_bounds__(256) void flash_attn(const bf16* __restrict__ Q,
                                                  const bf16* __restrict__ K,
                                                  const bf16* __restrict__ VT,
                                                  bf16* __restrict__ O) {
  const int qt = blockIdx.x;
  const int h = blockIdx.y;
  const int b = blockIdx.z;
  const int lane = threadIdx.x & 63, w = threadIdx.x >> 6;
  const int l16 = lane & 15, lq = lane >> 4;
  const int kvh = h >> 2;  // G = 4

  const bf16* Qb = Q + ((size_t)(b * NH + h) * SEQ) * DH;
  const bf16* Kb = K + ((size_t)(b * NKV + kvh) * SEQ) * DH;
  const bf16* Vb = VT + ((size_t)(b * NKV + kvh) * DH) * SEQ;

  const int qrow = qt * 64 + w * 16;

  bf16x8 qf[4];
#pragma unroll
  for (int kk = 0; kk < 4; ++kk)
    qf[kk] = *(const bf16x8*)&Qb[(size_t)(qrow + l16) * DH + kk * 32 + lq * 8];

  f32x4 acc[8] = {};
  float mrun[4], lrun[4];
#pragma unroll
  for (int r = 0; r < 4; ++r) {
    mrun[r] = -INFINITY;
    lrun[r] = 0.f;
  }

  __shared__ bf16 plds[4][16][72];  // wave-private P tiles, 144B row stride (16B-aligned, conflict-light)

  for (int tkv = 0; tkv <= qt; ++tkv) {
    f32x4 sacc[4] = {};
#pragma unroll
    for (int nt = 0; nt < 4; ++nt) {
      const bf16* kr = &Kb[(size_t)(tkv * 64 + nt * 16 + l16) * DH + lq * 8];
#pragma unroll
      for (int kk = 0; kk < 4; ++kk) {
        bf16x8 kf = *(const bf16x8*)(kr + kk * 32);
        sacc[nt] = __builtin_amdgcn_mfma_f32_16x16x32_bf16(qf[kk], kf, sacc[nt], 0, 0, 0);
      }
    }
    if (tkv == qt) {  // diagonal tile: causal mask
#pragma unroll
      for (int nt = 0; nt < 4; ++nt)
#pragma unroll
        for (int r = 0; r < 4; ++r) {
          const int sg = tkv * 64 + nt * 16 + l16;
          const int qg = qrow + lq * 4 + r;
          if (sg > qg) sacc[nt][r] = -INFINITY;
        }
    }
    float corr[4];
#pragma unroll
    for (int r = 0; r < 4; ++r) {
      float mx = fmaxf(fmaxf(sacc[0][r], sacc[1][r]), fmaxf(sacc[2][r], sacc[3][r]));
#pragma unroll
      for (int off = 1; off < 16; off <<= 1) mx = fmaxf(mx, __shfl_xor(mx, off));
      const float mnew = fmaxf(mrun[r], mx);
      corr[r] = __expf(mrun[r] - mnew);  // -inf -> 0 on first tile
      mrun[r] = mnew;
      float ps = 0.f;
#pragma unroll
      for (int nt = 0; nt < 4; ++nt) {
        const float pv = __expf(sacc[nt][r] - mnew);
        sacc[nt][r] = pv;
        ps += pv;
      }
#pragma unroll
      for (int off = 1; off < 16; off <<= 1) ps += __shfl_xor(ps, off);
      lrun[r] = lrun[r] * corr[r] + ps;
    }
#pragma unroll
    for (int j = 0; j < 8; ++j)
#pragma unroll
      for (int r = 0; r < 4; ++r) acc[j][r] *= corr[r];

    // P (C-layout) -> LDS -> A-layout fragments (wave-private; compiler inserts lgkmcnt waits)
#pragma unroll
    for (int nt = 0; nt < 4; ++nt)
#pragma unroll
      for (int r = 0; r < 4; ++r)
        plds[w][lq * 4 + r][nt * 16 + l16] = (bf16)sacc[nt][r];
    bf16x8 pf[2];
#pragma unroll
    for (int c = 0; c < 2; ++c)
      pf[c] = *(const bf16x8*)&plds[w][l16][c * 32 + lq * 8];

#pragma unroll
    for (int j = 0; j < 8; ++j) {
      const bf16* vr = &Vb[(size_t)(j * 16 + l16) * SEQ + tkv * 64 + lq * 8];
#pragma unroll
      for (int c = 0; c < 2; ++c) {
        bf16x8 vf = *(const bf16x8*)(vr + c * 32);
        acc[j] = __builtin_amdgcn_mfma_f32_16x16x32_bf16(pf[c], vf, acc[j], 0, 0, 0);
      }
    }
  }

  // epilogue: normalize, write attn_out [b][s][h*128+d] bf16
#pragma unroll
  for (int r = 0; r < 4; ++r) {
    const float inv = 1.f / lrun[r];
    const size_t orow = ((size_t)b * SEQ + qrow + lq * 4 + r) * HIDN + h * DH;
#pragma unroll
    for (int j = 0; j < 8; ++j) O[orow + j * 16 + l16] = (bf16)(acc[j][r] * inv);
  }
}

extern "C" void kernel_launch(void* const* d_in, const int* in_sizes, int n_in,
                              void* d_out, int out_size, void* d_ws, size_t ws_size,
                              hipStream_t stream) {
  const float* hidden = (const float*)d_in[0];
  const float* cosp = (const float*)d_in[1];
  const float* sinp = (const float*)d_in[2];
  const float* wqkv = (const float*)d_in[3];
  const float* wo = (const float*)d_in[4];
  float* out = (float*)d_out;

  char* ws = (char*)d_ws;
  // layout (bytes):
  bf16* hiddenB = (bf16*)(ws);                 // 16,777,216   [2048][4096]
  bf16* wqkvT  = (bf16*)(ws + 16777216);       // 50,331,648   [6144][4096]
  bf16* woT    = (bf16*)(ws + 67108864);       // 33,554,432   [4096][4096]
  bf16* qkvB   = (bf16*)(ws + 100663296);      // 25,165,824   [2048][6144]
  bf16* Qb     = (bf16*)(ws + 125829120);      // 16,777,216   [2][32][1024][128]
  bf16* Kb     = (bf16*)(ws + 142606336);      //  4,194,304   [2][8][1024][128]
  bf16* VTb    = (bf16*)(ws + 146800640);      //  4,194,304   [2][8][128][1024]
  bf16* attnB  = hiddenB;                      // alias: hiddenB dead after gemm1

  cvt_f32_bf16<<<8192, 256, 0, stream>>>(hidden, hiddenB, 2097152);
  transpose_cvt<<<dim3(192, 128), 256, 0, stream>>>(wqkv, wqkvT, 4096, 6144);
  transpose_cvt<<<dim3(128, 128), 256, 0, stream>>>(wo, woT, 4096, 4096);
  gemm_bt<1><<<dim3(48, 16), 256, 0, stream>>>(hiddenB, wqkvT, qkvB, 2048, 6144, 4096);
  rope_reshape<<<2048, 256, 0, stream>>>(qkvB, cosp, sinp, Qb, Kb, VTb);
  flash_attn<<<dim3(16, 32, 2), 256, 0, stream>>>(Qb, Kb, VTb, attnB);
  gemm_bt<0><<<dim3(32, 16), 256, 0, stream>>>(attnB, woT, out, 2048, 4096, 4096);
}

// Round 2
// 428.035 us; speedup vs baseline: 1.2380x; 1.2380x over previous
//
#include <hip/hip_runtime.h>
#include <hip/hip_bf16.h>

typedef __bf16 bf16;
typedef __attribute__((ext_vector_type(2))) __bf16 bf16x2;
typedef __attribute__((ext_vector_type(4))) __bf16 bf16x4;
typedef __attribute__((ext_vector_type(8))) __bf16 bf16x8;
typedef __attribute__((ext_vector_type(4))) float f32x4;

#define NB 2
#define SEQ 1024
#define HIDN 4096
#define NH 32
#define NKV 8
#define DH 128
#define QKV_N 6144
static constexpr float SCALE = 0.08838834764831845f;  // 1/sqrt(128)

#define MFMA(a, b, c) __builtin_amdgcn_mfma_f32_16x16x32_bf16((a), (b), (c), 0, 0, 0)

__device__ __forceinline__ void async16(const void* g, void* l) {
  __builtin_amdgcn_global_load_lds(
      (const __attribute__((address_space(1))) unsigned int*)g,
      (__attribute__((address_space(3))) unsigned int*)l,
      16, 0, 0);
}

// ---------------- f32 -> bf16 convert (vector) ----------------
__global__ __launch_bounds__(256) void cvt_f32_bf16(const float* __restrict__ src,
                                                    bf16* __restrict__ dst, int n4) {
  int i = blockIdx.x * 256 + threadIdx.x;
  if (i >= n4) return;
  const float4 v = ((const float4*)src)[i];
  bf16x4 o = {(bf16)v.x, (bf16)v.y, (bf16)v.z, (bf16)v.w};
  ((bf16x4*)dst)[i] = o;
}

// ---------------- transpose + convert: dst[N][K] = (bf16)src[K][N] ----------------
__global__ __launch_bounds__(256) void transpose_cvt(const float* __restrict__ src,
                                                     bf16* __restrict__ dst, int R, int C) {
  __shared__ float tl[32][33];
  const int j0 = blockIdx.x * 32, i0 = blockIdx.y * 32;
  const int tr = threadIdx.x >> 5, tc = threadIdx.x & 31;
#pragma unroll
  for (int p = 0; p < 4; ++p)
    tl[tr + p * 8][tc] = src[(size_t)(i0 + tr + p * 8) * C + j0 + tc];
  __syncthreads();
#pragma unroll
  for (int p = 0; p < 4; ++p)
    dst[(size_t)(j0 + tr + p * 8) * R + i0 + tc] = (bf16)tl[tc][tr + p * 8];
}

// ---------------- bf16 GEMM: C[M][N] = A[M][K] * BT[N][K]^T (m97 structure) ----------------
template <int OUT_BF16>
__global__ __launch_bounds__(256) void gemm_bt(const bf16* __restrict__ A,
                                               const bf16* __restrict__ BT,
                                               void* __restrict__ Cout,
                                               int M, int N, int K) {
  __shared__ bf16 As[128 * 32];
  __shared__ bf16 Bs[128 * 32];
  const int t = threadIdx.x;
  const int lane = t & 63, w = t >> 6;
  const int l16 = lane & 15, lq = lane >> 4;
  const int m0 = blockIdx.y * 128, n0 = blockIdx.x * 128;
  const int wr = (w >> 1) * 64, wc = (w & 1) * 64;
  const int sr = t >> 2;
  const int sc = (t & 3) * 8;
  const bf16* ga0 = A + (size_t)(m0 + sr) * K + sc;
  const bf16* ga1 = A + (size_t)(m0 + sr + 64) * K + sc;
  const bf16* gb0 = BT + (size_t)(n0 + sr) * K + sc;
  const bf16* gb1 = BT + (size_t)(n0 + sr + 64) * K + sc;
  char* lA = (char*)As + t * 16;
  char* lB = (char*)Bs + t * 16;

  f32x4 acc[4][4] = {};

  for (int kt = 0; kt < K; kt += 32) {
    __syncthreads();
    async16(ga0 + kt, lA);
    async16(ga1 + kt, lA + 4096);
    async16(gb0 + kt, lB);
    async16(gb1 + kt, lB + 4096);
    __syncthreads();
    bf16x8 af[4], bfr[4];
#pragma unroll
    for (int mt = 0; mt < 4; ++mt)
      af[mt] = *(const bf16x8*)&As[(wr + mt * 16 + l16) * 32 + lq * 8];
#pragma unroll
    for (int nt = 0; nt < 4; ++nt)
      bfr[nt] = *(const bf16x8*)&Bs[(wc + nt * 16 + l16) * 32 + lq * 8];
#pragma unroll
    for (int nt = 0; nt < 4; ++nt)
#pragma unroll
      for (int mt = 0; mt < 4; ++mt)
        acc[mt][nt] = MFMA(af[mt], bfr[nt], acc[mt][nt]);
  }

#pragma unroll
  for (int mt = 0; mt < 4; ++mt)
#pragma unroll
    for (int nt = 0; nt < 4; ++nt)
#pragma unroll
      for (int r = 0; r < 4; ++r) {
        const int row = m0 + wr + mt * 16 + lq * 4 + r;
        const int col = n0 + wc + nt * 16 + l16;
        const float v = acc[mt][nt][r];
        if (OUT_BF16)
          ((bf16*)Cout)[(size_t)row * N + col] = (bf16)v;
        else
          ((float*)Cout)[(size_t)row * N + col] = v;
      }
}

// ---------------- RoPE + reshape: qkv -> Q[b][h][s][d] (scaled), K[b][kv][s][d], VT[b][kv][d][s] ----------------
__global__ __launch_bounds__(256) void rope_reshape(const bf16* __restrict__ qkv,
                                                    const float* __restrict__ cosp,
                                                    const float* __restrict__ sinp,
                                                    bf16* __restrict__ Qo,
                                                    bf16* __restrict__ Ko,
                                                    bf16* __restrict__ VTo) {
  const int row = blockIdx.x;          // b*SEQ + s
  const int b = row >> 10, s = row & 1023;
  const bf16* src = qkv + (size_t)row * QKV_N;
  for (int p = threadIdx.x; p < QKV_N / 2; p += 256) {
    const int col = p * 2;
    bf16x2 x = *(const bf16x2*)&src[col];
    const float x1 = (float)x.x, x2 = (float)x.y;
    if (col < 4096) {
      const int h = col >> 7, d = col & 127, i = (col & 127) >> 1;
      const float c = cosp[s * 64 + i], sn = sinp[s * 64 + i];
      bf16x2 o = {(bf16)((x1 * c - x2 * sn) * SCALE), (bf16)((x1 * sn + x2 * c) * SCALE)};
      *(bf16x2*)&Qo[((size_t)(b * NH + h) * SEQ + s) * DH + d] = o;
    } else if (col < 5120) {
      const int idx = col - 4096;
      const int kvh = idx >> 7, d = idx & 127, i = (idx & 127) >> 1;
      const float c = cosp[s * 64 + i], sn = sinp[s * 64 + i];
      bf16x2 o = {(bf16)(x1 * c - x2 * sn), (bf16)(x1 * sn + x2 * c)};
      *(bf16x2*)&Ko[((size_t)(b * NKV + kvh) * SEQ + s) * DH + d] = o;
    } else {
      const int idx = col - 5120;
      const int kvh = idx >> 7, d = idx & 127;
      bf16* vbase = VTo + ((size_t)(b * NKV + kvh) * DH + d) * SEQ + s;
      vbase[0] = x.x;
      vbase[SEQ] = x.y;
    }
  }
}

// ---------------- causal GQA flash attention, paired q-tiles ----------------
// 2048 waves; wave p handles q-tiles t=p&31 and 63-t of head (p>>5)&31, batch p>>10.
// Work per wave = (t/4+1) + ((63-t)/4+1) = 16..17 KV tiles -> perfectly balanced.
// Within the common KV prefix both tiles share K/V fragment loads (2 indep MFMA streams).
__global__ __launch_bounds__(256, 2) void flash_attn(const bf16* __restrict__ Q,
                                                     const bf16* __restrict__ K,
                                                     const bf16* __restrict__ VT,
                                                     bf16* __restrict__ O) {
  const int lane = threadIdx.x & 63, w = threadIdx.x >> 6;
  const int l16 = lane & 15, lq = lane >> 4;
  const int p = blockIdx.x * 4 + w;  // 0..2047
  const int b = p >> 10, h = (p >> 5) & 31, t = p & 31;
  const int kvh = h >> 2;  // G = 4

  const bf16* Qb = Q + (size_t)(b * NH + h) * SEQ * DH;
  const bf16* Kb = K + (size_t)(b * NKV + kvh) * SEQ * DH;
  const bf16* Vb = VT + (size_t)(b * NKV + kvh) * DH * SEQ;

  const int qrA = t * 16, qrB = (63 - t) * 16;
  const int nA = t / 4 + 1, nB = (63 - t) / 4 + 1;  // nB > nA always (t<32)

  __shared__ bf16 plds[4][2][16][72];  // wave-private P tiles

  bf16x8 qfA[4], qfB[4];
#pragma unroll
  for (int kk = 0; kk < 4; ++kk) {
    qfA[kk] = *(const bf16x8*)&Qb[(size_t)(qrA + l16) * DH + kk * 32 + lq * 8];
    qfB[kk] = *(const bf16x8*)&Qb[(size_t)(qrB + l16) * DH + kk * 32 + lq * 8];
  }

  f32x4 accA[8] = {}, accB[8] = {};
  float mA[4], lA[4], mB[4], lB[4];
#pragma unroll
  for (int r = 0; r < 4; ++r) {
    mA[r] = mB[r] = -INFINITY;
    lA[r] = lB[r] = 0.f;
  }

  // online-softmax finish for one tile: mask, row-reduce, exp, rescale acc, P->LDS
  auto finish = [&](f32x4(&s)[4], float(&m)[4], float(&l)[4], f32x4(&acc)[8], int slot,
                    bool mask, int kv, int qr) {
    if (mask) {
#pragma unroll
      for (int nt = 0; nt < 4; ++nt)
#pragma unroll
        for (int r = 0; r < 4; ++r)
          if (kv * 64 + nt * 16 + l16 > qr + lq * 4 + r) s[nt][r] = -INFINITY;
    }
#pragma unroll
    for (int r = 0; r < 4; ++r) {
      float mx = fmaxf(fmaxf(s[0][r], s[1][r]), fmaxf(s[2][r], s[3][r]));
#pragma unroll
      for (int off = 1; off < 16; off <<= 1) mx = fmaxf(mx, __shfl_xor(mx, off));
      const float mn = fmaxf(m[r], mx);
      const float corr = __expf(m[r] - mn);
      m[r] = mn;
      float ps = 0.f;
#pragma unroll
      for (int nt = 0; nt < 4; ++nt) {
        const float pv = __expf(s[nt][r] - mn);
        s[nt][r] = pv;
        ps += pv;
      }
#pragma unroll
      for (int off = 1; off < 16; off <<= 1) ps += __shfl_xor(ps, off);
      l[r] = l[r] * corr + ps;
#pragma unroll
      for (int j = 0; j < 8; ++j) acc[j][r] *= corr;
    }
#pragma unroll
    for (int nt = 0; nt < 4; ++nt)
#pragma unroll
      for (int r = 0; r < 4; ++r)
        plds[w][slot][lq * 4 + r][nt * 16 + l16] = (bf16)s[nt][r];
  };

  int kv = 0;
  // ---- common prefix: both tiles, shared K/V loads ----
  for (; kv < nA; ++kv) {
    f32x4 sA[4] = {}, sB[4] = {};
    const bf16* kbase = &Kb[(size_t)(kv * 64 + l16) * DH + lq * 8];
#pragma unroll
    for (int nt = 0; nt < 4; ++nt) {
      const bf16* kr = kbase + (size_t)nt * 16 * DH;
      bf16x8 k0 = *(const bf16x8*)kr;
      bf16x8 k1 = *(const bf16x8*)(kr + 32);
      bf16x8 k2 = *(const bf16x8*)(kr + 64);
      bf16x8 k3 = *(const bf16x8*)(kr + 96);
      sA[nt] = MFMA(qfA[0], k0, sA[nt]);
      sB[nt] = MFMA(qfB[0], k0, sB[nt]);
      sA[nt] = MFMA(qfA[1], k1, sA[nt]);
      sB[nt] = MFMA(qfB[1], k1, sB[nt]);
      sA[nt] = MFMA(qfA[2], k2, sA[nt]);
      sB[nt] = MFMA(qfB[2], k2, sB[nt]);
      sA[nt] = MFMA(qfA[3], k3, sA[nt]);
      sB[nt] = MFMA(qfB[3], k3, sB[nt]);
    }
    finish(sA, mA, lA, accA, 0, kv == nA - 1, kv, qrA);
    finish(sB, mB, lB, accB, 1, false, kv, qrB);
    bf16x8 pA0 = *(const bf16x8*)&plds[w][0][l16][lq * 8];
    bf16x8 pA1 = *(const bf16x8*)&plds[w][0][l16][32 + lq * 8];
    bf16x8 pB0 = *(const bf16x8*)&plds[w][1][l16][lq * 8];
    bf16x8 pB1 = *(const bf16x8*)&plds[w][1][l16][32 + lq * 8];
    const bf16* vbase = &Vb[(size_t)l16 * SEQ + kv * 64 + lq * 8];
#pragma unroll
    for (int j = 0; j < 8; ++j) {
      const bf16* vr = vbase + (size_t)j * 16 * SEQ;
      bf16x8 v0 = *(const bf16x8*)vr;
      bf16x8 v1 = *(const bf16x8*)(vr + 32);
      accA[j] = MFMA(pA0, v0, accA[j]);
      accB[j] = MFMA(pB0, v0, accB[j]);
      accA[j] = MFMA(pA1, v1, accA[j]);
      accB[j] = MFMA(pB1, v1, accB[j]);
    }
  }
  // ---- tail: tile B only ----
  for (; kv < nB; ++kv) {
    f32x4 sB[4] = {};
    const bf16* kbase = &Kb[(size_t)(kv * 64 + l16) * DH + lq * 8];
#pragma unroll
    for (int nt = 0; nt < 4; ++nt) {
      const bf16* kr = kbase + (size_t)nt * 16 * DH;
      bf16x8 k0 = *(const bf16x8*)kr;
      bf16x8 k1 = *(const bf16x8*)(kr + 32);
      bf16x8 k2 = *(const bf16x8*)(kr + 64);
      bf16x8 k3 = *(const bf16x8*)(kr + 96);
      sB[nt] = MFMA(qfB[0], k0, sB[nt]);
      sB[nt] = MFMA(qfB[1], k1, sB[nt]);
      sB[nt] = MFMA(qfB[2], k2, sB[nt]);
      sB[nt] = MFMA(qfB[3], k3, sB[nt]);
    }
    finish(sB, mB, lB, accB, 1, kv == nB - 1, kv, qrB);
    bf16x8 pB0 = *(const bf16x8*)&plds[w][1][l16][lq * 8];
    bf16x8 pB1 = *(const bf16x8*)&plds[w][1][l16][32 + lq * 8];
    const bf16* vbase = &Vb[(size_t)l16 * SEQ + kv * 64 + lq * 8];
#pragma unroll
    for (int j = 0; j < 8; ++j) {
      const bf16* vr = vbase + (size_t)j * 16 * SEQ;
      bf16x8 v0 = *(const bf16x8*)vr;
      bf16x8 v1 = *(const bf16x8*)(vr + 32);
      accB[j] = MFMA(pB0, v0, accB[j]);
      accB[j] = MFMA(pB1, v1, accB[j]);
    }
  }

  // epilogue: normalize, write attn_out [b][s][h*128+d] bf16
  auto wout = [&](f32x4(&acc)[8], float(&l)[4], int qr) {
#pragma unroll
    for (int r = 0; r < 4; ++r) {
      const float inv = 1.f / l[r];
      const size_t orow = ((size_t)b * SEQ + qr + lq * 4 + r) * HIDN + h * DH;
#pragma unroll
      for (int j = 0; j < 8; ++j) O[orow + j * 16 + l16] = (bf16)(acc[j][r] * inv);
    }
  };
  wout(accA, lA, qrA);
  wout(accB, lB, qrB);
}

extern "C" void kernel_launch(void* const* d_in, const int* in_sizes, int n_in,
                              void* d_out, int out_size, void* d_ws, size_t ws_size,
                              hipStream_t stream) {
  const float* hidden = (const float*)d_in[0];
  const float* cosp = (const float*)d_in[1];
  const float* sinp = (const float*)d_in[2];
  const float* wqkv = (const float*)d_in[3];
  const float* wo = (const float*)d_in[4];
  float* out = (float*)d_out;

  char* ws = (char*)d_ws;
  bf16* hiddenB = (bf16*)(ws);                 // 16,777,216   [2048][4096]
  bf16* wqkvT  = (bf16*)(ws + 16777216);       // 50,331,648   [6144][4096]
  bf16* woT    = (bf16*)(ws + 67108864);       // 33,554,432   [4096][4096]
  bf16* qkvB   = (bf16*)(ws + 100663296);      // 25,165,824   [2048][6144]
  bf16* Qb     = (bf16*)(ws + 125829120);      // 16,777,216   [2][32][1024][128]
  bf16* Kb     = (bf16*)(ws + 142606336);      //  4,194,304   [2][8][1024][128]
  bf16* VTb    = (bf16*)(ws + 146800640);      //  4,194,304   [2][8][128][1024]
  bf16* attnB  = hiddenB;                      // alias: hiddenB dead after gemm1

  cvt_f32_bf16<<<8192, 256, 0, stream>>>(hidden, hiddenB, 2097152);
  transpose_cvt<<<dim3(192, 128), 256, 0, stream>>>(wqkv, wqkvT, 4096, 6144);
  transpose_cvt<<<dim3(128, 128), 256, 0, stream>>>(wo, woT, 4096, 4096);
  gemm_bt<1><<<dim3(48, 16), 256, 0, stream>>>(hiddenB, wqkvT, qkvB, 2048, 6144, 4096);
  rope_reshape<<<2048, 256, 0, stream>>>(qkvB, cosp, sinp, Qb, Kb, VTb);
  flash_attn<<<dim3(512), 256, 0, stream>>>(Qb, Kb, VTb, attnB);
  gemm_bt<0><<<dim3(32, 16), 256, 0, stream>>>(attnB, woT, out, 2048, 4096, 4096);
}

// Round 3
// 406.702 us; speedup vs baseline: 1.3029x; 1.0525x over previous
//
#include <hip/hip_runtime.h>
#include <hip/hip_bf16.h>

typedef __bf16 bf16;
typedef __attribute__((ext_vector_type(2))) __bf16 bf16x2;
typedef __attribute__((ext_vector_type(4))) __bf16 bf16x4;
typedef __attribute__((ext_vector_type(8))) __bf16 bf16x8;
typedef __attribute__((ext_vector_type(4))) float f32x4;

#define NB 2
#define SEQ 1024
#define HIDN 4096
#define NH 32
#define NKV 8
#define DH 128
#define QKV_N 6144
static constexpr float SCALE = 0.08838834764831845f;  // 1/sqrt(128)

#define MFMA(a, b, c) __builtin_amdgcn_mfma_f32_16x16x32_bf16((a), (b), (c), 0, 0, 0)

__device__ __forceinline__ void async16(const void* g, void* l) {
  __builtin_amdgcn_global_load_lds(
      (const __attribute__((address_space(1))) unsigned int*)g,
      (__attribute__((address_space(3))) unsigned int*)l,
      16, 0, 0);
}

__device__ __forceinline__ void barrier_raw() {
  asm volatile("" ::: "memory");
  __builtin_amdgcn_s_barrier();
  asm volatile("" ::: "memory");
}
#define VMCNT(n) asm volatile("s_waitcnt vmcnt(" #n ")" ::: "memory")

// ---------------- f32 -> bf16 convert (vector) ----------------
__global__ __launch_bounds__(256) void cvt_f32_bf16(const float* __restrict__ src,
                                                    bf16* __restrict__ dst, int n4) {
  int i = blockIdx.x * 256 + threadIdx.x;
  if (i >= n4) return;
  const float4 v = ((const float4*)src)[i];
  bf16x4 o = {(bf16)v.x, (bf16)v.y, (bf16)v.z, (bf16)v.w};
  ((bf16x4*)dst)[i] = o;
}

// ---------------- transpose + convert: dst[N][K] = (bf16)src[K][N] ----------------
__global__ __launch_bounds__(256) void transpose_cvt(const float* __restrict__ src,
                                                     bf16* __restrict__ dst, int R, int C) {
  __shared__ float tl[32][33];
  const int j0 = blockIdx.x * 32, i0 = blockIdx.y * 32;
  const int tr = threadIdx.x >> 5, tc = threadIdx.x & 31;
#pragma unroll
  for (int p = 0; p < 4; ++p)
    tl[tr + p * 8][tc] = src[(size_t)(i0 + tr + p * 8) * C + j0 + tc];
  __syncthreads();
#pragma unroll
  for (int p = 0; p < 4; ++p)
    dst[(size_t)(j0 + tr + p * 8) * R + i0 + tc] = (bf16)tl[tc][tr + p * 8];
}

// ---------------- deep-prefetch bf16 GEMM: C[M][N] = A[M][K] * BT[N][K]^T ----------------
// BM=256, BK=32, 8 waves (512 thr), 4 LDS K-tile buffers, prefetch distance 3,
// counted vmcnt (T4), raw barriers (T3-lite), LDS swizzle byte^=((byte>>7)&3)<<4 (T2),
// bijective XCD chunk swizzle (T1), setprio around MFMA (T5).
template <int BN, int OUT_BF16>
__global__ __launch_bounds__(512, 2) void gemm8p(const bf16* __restrict__ A,
                                                 const bf16* __restrict__ BT,
                                                 void* __restrict__ Cout,
                                                 int M, int N, int K, int nbn) {
  extern __shared__ char smem[];
  constexpr int ABYTES = 256 * 32 * 2;   // 16 KiB
  constexpr int BBYTES = BN * 32 * 2;    // 16 / 8 KiB
  constexpr int BUFB = ABYTES + BBYTES;  // per K-tile buffer
  constexpr int WROWS = (BN == 256) ? 2 : 4;
  constexpr int WCOLS = 8 / WROWS;
  constexpr int FM = 256 / WROWS / 16;  // 8 / 4
  constexpr int FN = BN / WCOLS / 16;   // 4 / 4
  constexpr int LA = 2;                 // A stage instr / thread / K-tile
  constexpr int LB = BBYTES / 8192;     // 2 / 1
  const int t = threadIdx.x;
  const int lane = t & 63, w = t >> 6;
  const int l16 = lane & 15, lq = lane >> 4;

  const int nwg = gridDim.x;  // divisible by 8
  const int lin = ((int)blockIdx.x & 7) * (nwg >> 3) + ((int)blockIdx.x >> 3);
  const int m0 = (lin / nbn) * 256;
  const int n0 = (lin % nbn) * BN;

  const int wrow = (w % WROWS) * (256 / WROWS);
  const int wcol = (w / WROWS) * (BN / WCOLS);

  // staging source pointers (pre-swizzled global source, linear LDS dest)
  const bf16* gA[LA];
  const bf16* gB[LB];
#pragma unroll
  for (int l = 0; l < LA; ++l) {
    const int row = (t >> 2) + l * 128;
    const int slot = (t & 3) ^ ((row >> 1) & 3);
    gA[l] = A + (size_t)(m0 + row) * K + slot * 8;
  }
#pragma unroll
  for (int l = 0; l < LB; ++l) {
    const int row = (t >> 2) + l * 128;
    const int slot = (t & 3) ^ ((row >> 1) & 3);
    gB[l] = BT + (size_t)(n0 + row) * K + slot * 8;
  }

  // precomputed swizzled LDS byte offsets for fragment reads
  int aoff[FM], boff[FN];
#pragma unroll
  for (int fm = 0; fm < FM; ++fm) {
    const int row = wrow + fm * 16 + l16;
    aoff[fm] = row * 64 + ((lq ^ ((row >> 1) & 3)) << 4);
  }
#pragma unroll
  for (int fn = 0; fn < FN; ++fn) {
    const int row = wcol + fn * 16 + l16;
    boff[fn] = ABYTES + row * 64 + ((lq ^ ((row >> 1) & 3)) << 4);
  }

  auto stage = [&](int kt) {
    char* dst = smem + (kt & 3) * BUFB + t * 16;
#pragma unroll
    for (int l = 0; l < LA; ++l) async16(gA[l] + (size_t)kt * 32, dst + l * 8192);
#pragma unroll
    for (int l = 0; l < LB; ++l) async16(gB[l] + (size_t)kt * 32, dst + ABYTES + l * 8192);
  };

  f32x4 acc[FM][FN] = {};
  const int NT = K >> 5;

  stage(0);
  stage(1);
  stage(2);

  for (int kt = 0; kt < NT; ++kt) {
    const char* buf = smem + (kt & 3) * BUFB;
    barrier_raw();  // everyone done reading buf[(kt+3)&3]'s previous tile
    if (kt + 3 < NT) {
      stage(kt + 3);
      if constexpr (BN == 256) VMCNT(12); else VMCNT(9);
    } else if (kt + 2 < NT) {
      if constexpr (BN == 256) VMCNT(8); else VMCNT(6);
    } else if (kt + 1 < NT) {
      if constexpr (BN == 256) VMCNT(4); else VMCNT(3);
    } else {
      VMCNT(0);
    }
    barrier_raw();  // everyone's stage(kt) landed

    bf16x8 bfrag[FN];
#pragma unroll
    for (int fn = 0; fn < FN; ++fn) bfrag[fn] = *(const bf16x8*)(buf + boff[fn]);
    __builtin_amdgcn_s_setprio(1);
#pragma unroll
    for (int fm = 0; fm < FM; ++fm) {
      bf16x8 af = *(const bf16x8*)(buf + aoff[fm]);
#pragma unroll
      for (int fn = 0; fn < FN; ++fn) acc[fm][fn] = MFMA(af, bfrag[fn], acc[fm][fn]);
    }
    __builtin_amdgcn_s_setprio(0);
  }

#pragma unroll
  for (int fm = 0; fm < FM; ++fm)
#pragma unroll
    for (int fn = 0; fn < FN; ++fn)
#pragma unroll
      for (int r = 0; r < 4; ++r) {
        const int row = m0 + wrow + fm * 16 + lq * 4 + r;
        const int col = n0 + wcol + fn * 16 + l16;
        if (OUT_BF16)
          ((bf16*)Cout)[(size_t)row * N + col] = (bf16)acc[fm][fn][r];
        else
          ((float*)Cout)[(size_t)row * N + col] = acc[fm][fn][r];
      }
}

// ---------------- RoPE + reshape: qkv -> Q[b][h][s][d] (scaled), K[b][kv][s][d], VT[b][kv][d][s] ----------------
__global__ __launch_bounds__(256) void rope_reshape(const bf16* __restrict__ qkv,
                                                    const float* __restrict__ cosp,
                                                    const float* __restrict__ sinp,
                                                    bf16* __restrict__ Qo,
                                                    bf16* __restrict__ Ko,
                                                    bf16* __restrict__ VTo) {
  const int row = blockIdx.x;          // b*SEQ + s
  const int b = row >> 10, s = row & 1023;
  const bf16* src = qkv + (size_t)row * QKV_N;
  for (int p = threadIdx.x; p < QKV_N / 2; p += 256) {
    const int col = p * 2;
    bf16x2 x = *(const bf16x2*)&src[col];
    const float x1 = (float)x.x, x2 = (float)x.y;
    if (col < 4096) {
      const int h = col >> 7, d = col & 127, i = (col & 127) >> 1;
      const float c = cosp[s * 64 + i], sn = sinp[s * 64 + i];
      bf16x2 o = {(bf16)((x1 * c - x2 * sn) * SCALE), (bf16)((x1 * sn + x2 * c) * SCALE)};
      *(bf16x2*)&Qo[((size_t)(b * NH + h) * SEQ + s) * DH + d] = o;
    } else if (col < 5120) {
      const int idx = col - 4096;
      const int kvh = idx >> 7, d = idx & 127, i = (idx & 127) >> 1;
      const float c = cosp[s * 64 + i], sn = sinp[s * 64 + i];
      bf16x2 o = {(bf16)(x1 * c - x2 * sn), (bf16)(x1 * sn + x2 * c)};
      *(bf16x2*)&Ko[((size_t)(b * NKV + kvh) * SEQ + s) * DH + d] = o;
    } else {
      const int idx = col - 5120;
      const int kvh = idx >> 7, d = idx & 127;
      bf16* vbase = VTo + ((size_t)(b * NKV + kvh) * DH + d) * SEQ + s;
      vbase[0] = x.x;
      vbase[SEQ] = x.y;
    }
  }
}

// ---------------- causal GQA flash attention, paired q-tiles ----------------
__global__ __launch_bounds__(256, 2) void flash_attn(const bf16* __restrict__ Q,
                                                     const bf16* __restrict__ K,
                                                     const bf16* __restrict__ VT,
                                                     bf16* __restrict__ O) {
  const int lane = threadIdx.x & 63, w = threadIdx.x >> 6;
  const int l16 = lane & 15, lq = lane >> 4;
  const int p = blockIdx.x * 4 + w;  // 0..2047
  const int b = p >> 10, h = (p >> 5) & 31, t = p & 31;
  const int kvh = h >> 2;  // G = 4

  const bf16* Qb = Q + (size_t)(b * NH + h) * SEQ * DH;
  const bf16* Kb = K + (size_t)(b * NKV + kvh) * SEQ * DH;
  const bf16* Vb = VT + (size_t)(b * NKV + kvh) * DH * SEQ;

  const int qrA = t * 16, qrB = (63 - t) * 16;
  const int nA = t / 4 + 1, nB = (63 - t) / 4 + 1;

  __shared__ bf16 plds[4][2][16][72];

  bf16x8 qfA[4], qfB[4];
#pragma unroll
  for (int kk = 0; kk < 4; ++kk) {
    qfA[kk] = *(const bf16x8*)&Qb[(size_t)(qrA + l16) * DH + kk * 32 + lq * 8];
    qfB[kk] = *(const bf16x8*)&Qb[(size_t)(qrB + l16) * DH + kk * 32 + lq * 8];
  }

  f32x4 accA[8] = {}, accB[8] = {};
  float mA[4], lA[4], mB[4], lB[4];
#pragma unroll
  for (int r = 0; r < 4; ++r) {
    mA[r] = mB[r] = -INFINITY;
    lA[r] = lB[r] = 0.f;
  }

  auto finish = [&](f32x4(&s)[4], float(&m)[4], float(&l)[4], f32x4(&acc)[8], int slot,
                    bool mask, int kv, int qr) {
    if (mask) {
#pragma unroll
      for (int nt = 0; nt < 4; ++nt)
#pragma unroll
        for (int r = 0; r < 4; ++r)
          if (kv * 64 + nt * 16 + l16 > qr + lq * 4 + r) s[nt][r] = -INFINITY;
    }
#pragma unroll
    for (int r = 0; r < 4; ++r) {
      float mx = fmaxf(fmaxf(s[0][r], s[1][r]), fmaxf(s[2][r], s[3][r]));
#pragma unroll
      for (int off = 1; off < 16; off <<= 1) mx = fmaxf(mx, __shfl_xor(mx, off));
      const float mn = fmaxf(m[r], mx);
      const float corr = __expf(m[r] - mn);
      m[r] = mn;
      float ps = 0.f;
#pragma unroll
      for (int nt = 0; nt < 4; ++nt) {
        const float pv = __expf(s[nt][r] - mn);
        s[nt][r] = pv;
        ps += pv;
      }
#pragma unroll
      for (int off = 1; off < 16; off <<= 1) ps += __shfl_xor(ps, off);
      l[r] = l[r] * corr + ps;
#pragma unroll
      for (int j = 0; j < 8; ++j) acc[j][r] *= corr;
    }
#pragma unroll
    for (int nt = 0; nt < 4; ++nt)
#pragma unroll
      for (int r = 0; r < 4; ++r)
        plds[w][slot][lq * 4 + r][nt * 16 + l16] = (bf16)s[nt][r];
  };

  int kv = 0;
  for (; kv < nA; ++kv) {
    f32x4 sA[4] = {}, sB[4] = {};
    const bf16* kbase = &Kb[(size_t)(kv * 64 + l16) * DH + lq * 8];
#pragma unroll
    for (int nt = 0; nt < 4; ++nt) {
      const bf16* kr = kbase + (size_t)nt * 16 * DH;
      bf16x8 k0 = *(const bf16x8*)kr;
      bf16x8 k1 = *(const bf16x8*)(kr + 32);
      bf16x8 k2 = *(const bf16x8*)(kr + 64);
      bf16x8 k3 = *(const bf16x8*)(kr + 96);
      sA[nt] = MFMA(qfA[0], k0, sA[nt]);
      sB[nt] = MFMA(qfB[0], k0, sB[nt]);
      sA[nt] = MFMA(qfA[1], k1, sA[nt]);
      sB[nt] = MFMA(qfB[1], k1, sB[nt]);
      sA[nt] = MFMA(qfA[2], k2, sA[nt]);
      sB[nt] = MFMA(qfB[2], k2, sB[nt]);
      sA[nt] = MFMA(qfA[3], k3, sA[nt]);
      sB[nt] = MFMA(qfB[3], k3, sB[nt]);
    }
    finish(sA, mA, lA, accA, 0, kv == nA - 1, kv, qrA);
    finish(sB, mB, lB, accB, 1, false, kv, qrB);
    bf16x8 pA0 = *(const bf16x8*)&plds[w][0][l16][lq * 8];
    bf16x8 pA1 = *(const bf16x8*)&plds[w][0][l16][32 + lq * 8];
    bf16x8 pB0 = *(const bf16x8*)&plds[w][1][l16][lq * 8];
    bf16x8 pB1 = *(const bf16x8*)&plds[w][1][l16][32 + lq * 8];
    const bf16* vbase = &Vb[(size_t)l16 * SEQ + kv * 64 + lq * 8];
#pragma unroll
    for (int j = 0; j < 8; ++j) {
      const bf16* vr = vbase + (size_t)j * 16 * SEQ;
      bf16x8 v0 = *(const bf16x8*)vr;
      bf16x8 v1 = *(const bf16x8*)(vr + 32);
      accA[j] = MFMA(pA0, v0, accA[j]);
      accB[j] = MFMA(pB0, v0, accB[j]);
      accA[j] = MFMA(pA1, v1, accA[j]);
      accB[j] = MFMA(pB1, v1, accB[j]);
    }
  }
  for (; kv < nB; ++kv) {
    f32x4 sB[4] = {};
    const bf16* kbase = &Kb[(size_t)(kv * 64 + l16) * DH + lq * 8];
#pragma unroll
    for (int nt = 0; nt < 4; ++nt) {
      const bf16* kr = kbase + (size_t)nt * 16 * DH;
      bf16x8 k0 = *(const bf16x8*)kr;
      bf16x8 k1 = *(const bf16x8*)(kr + 32);
      bf16x8 k2 = *(const bf16x8*)(kr + 64);
      bf16x8 k3 = *(const bf16x8*)(kr + 96);
      sB[nt] = MFMA(qfB[0], k0, sB[nt]);
      sB[nt] = MFMA(qfB[1], k1, sB[nt]);
      sB[nt] = MFMA(qfB[2], k2, sB[nt]);
      sB[nt] = MFMA(qfB[3], k3, sB[nt]);
    }
    finish(sB, mB, lB, accB, 1, kv == nB - 1, kv, qrB);
    bf16x8 pB0 = *(const bf16x8*)&plds[w][1][l16][lq * 8];
    bf16x8 pB1 = *(const bf16x8*)&plds[w][1][l16][32 + lq * 8];
    const bf16* vbase = &Vb[(size_t)l16 * SEQ + kv * 64 + lq * 8];
#pragma unroll
    for (int j = 0; j < 8; ++j) {
      const bf16* vr = vbase + (size_t)j * 16 * SEQ;
      bf16x8 v0 = *(const bf16x8*)vr;
      bf16x8 v1 = *(const bf16x8*)(vr + 32);
      accB[j] = MFMA(pB0, v0, accB[j]);
      accB[j] = MFMA(pB1, v1, accB[j]);
    }
  }

  auto wout = [&](f32x4(&acc)[8], float(&l)[4], int qr) {
#pragma unroll
    for (int r = 0; r < 4; ++r) {
      const float inv = 1.f / l[r];
      const size_t orow = ((size_t)b * SEQ + qr + lq * 4 + r) * HIDN + h * DH;
#pragma unroll
      for (int j = 0; j < 8; ++j) O[orow + j * 16 + l16] = (bf16)(acc[j][r] * inv);
    }
  };
  wout(accA, lA, qrA);
  wout(accB, lB, qrB);
}

extern "C" void kernel_launch(void* const* d_in, const int* in_sizes, int n_in,
                              void* d_out, int out_size, void* d_ws, size_t ws_size,
                              hipStream_t stream) {
  const float* hidden = (const float*)d_in[0];
  const float* cosp = (const float*)d_in[1];
  const float* sinp = (const float*)d_in[2];
  const float* wqkv = (const float*)d_in[3];
  const float* wo = (const float*)d_in[4];
  float* out = (float*)d_out;

  char* ws = (char*)d_ws;
  bf16* hiddenB = (bf16*)(ws);                 // 16,777,216   [2048][4096]
  bf16* wqkvT  = (bf16*)(ws + 16777216);       // 50,331,648   [6144][4096]
  bf16* woT    = (bf16*)(ws + 67108864);       // 33,554,432   [4096][4096]
  bf16* qkvB   = (bf16*)(ws + 100663296);      // 25,165,824   [2048][6144]
  bf16* Qb     = (bf16*)(ws + 125829120);      // 16,777,216   [2][32][1024][128]
  bf16* Kb     = (bf16*)(ws + 142606336);      //  4,194,304   [2][8][1024][128]
  bf16* VTb    = (bf16*)(ws + 146800640);      //  4,194,304   [2][8][128][1024]
  bf16* attnB  = hiddenB;                      // alias: hiddenB dead after gemm1

  cvt_f32_bf16<<<8192, 256, 0, stream>>>(hidden, hiddenB, 2097152);
  transpose_cvt<<<dim3(192, 128), 256, 0, stream>>>(wqkv, wqkvT, 4096, 6144);
  transpose_cvt<<<dim3(128, 128), 256, 0, stream>>>(wo, woT, 4096, 4096);
  gemm8p<256, 1><<<dim3(192), 512, 131072, stream>>>(hiddenB, wqkvT, qkvB, 2048, 6144, 4096, 24);
  rope_reshape<<<2048, 256, 0, stream>>>(qkvB, cosp, sinp, Qb, Kb, VTb);
  flash_attn<<<dim3(512), 256, 0, stream>>>(Qb, Kb, VTb, attnB);
  gemm8p<128, 0><<<dim3(256), 512, 98304, stream>>>(attnB, woT, out, 2048, 4096, 4096, 32);
}

// Round 4
// 401.953 us; speedup vs baseline: 1.3183x; 1.0118x over previous
//
#include <hip/hip_runtime.h>
#include <hip/hip_bf16.h>

typedef __bf16 bf16;
typedef __attribute__((ext_vector_type(2))) __bf16 bf16x2;
typedef __attribute__((ext_vector_type(4))) __bf16 bf16x4;
typedef __attribute__((ext_vector_type(8))) __bf16 bf16x8;
typedef __attribute__((ext_vector_type(4))) float f32x4;

#define NB 2
#define SEQ 1024
#define HIDN 4096
#define NH 32
#define NKV 8
#define DH 128
#define QKV_N 6144
static constexpr float SCALE = 0.08838834764831845f;  // 1/sqrt(128)

#define MFMA(a, b, c) __builtin_amdgcn_mfma_f32_16x16x32_bf16((a), (b), (c), 0, 0, 0)

__device__ __forceinline__ void async16(const void* g, void* l) {
  __builtin_amdgcn_global_load_lds(
      (const __attribute__((address_space(1))) unsigned int*)g,
      (__attribute__((address_space(3))) unsigned int*)l,
      16, 0, 0);
}

__device__ __forceinline__ void barrier_raw() {
  asm volatile("" ::: "memory");
  __builtin_amdgcn_s_barrier();
  asm volatile("" ::: "memory");
}
#define VMCNT(n) asm volatile("s_waitcnt vmcnt(" #n ")" ::: "memory")

// ---------------- f32 -> bf16 convert (vector) ----------------
__global__ __launch_bounds__(256) void cvt_f32_bf16(const float* __restrict__ src,
                                                    bf16* __restrict__ dst, int n4) {
  int i = blockIdx.x * 256 + threadIdx.x;
  if (i >= n4) return;
  const float4 v = ((const float4*)src)[i];
  bf16x4 o = {(bf16)v.x, (bf16)v.y, (bf16)v.z, (bf16)v.w};
  ((bf16x4*)dst)[i] = o;
}

// ---------------- transpose + convert: dst[N][K] = (bf16)src[K][N] ----------------
__global__ __launch_bounds__(256) void transpose_cvt(const float* __restrict__ src,
                                                     bf16* __restrict__ dst, int R, int C) {
  __shared__ float tl[32][33];
  const int j0 = blockIdx.x * 32, i0 = blockIdx.y * 32;
  const int tr = threadIdx.x >> 5, tc = threadIdx.x & 31;
#pragma unroll
  for (int p = 0; p < 4; ++p)
    tl[tr + p * 8][tc] = src[(size_t)(i0 + tr + p * 8) * C + j0 + tc];
  __syncthreads();
#pragma unroll
  for (int p = 0; p < 4; ++p)
    dst[(size_t)(j0 + tr + p * 8) * R + i0 + tc] = (bf16)tl[tc][tr + p * 8];
}

// ---------------- co-resident deep-prefetch bf16 GEMM ----------------
// C[M][N] = A[M][K] * BT[N][K]^T.  BM=BN=128, BK=32, 256 thr (4 waves 2x2),
// 3 rotating LDS K-tile buffers (48 KB -> 3 blocks/CU), prefetch depth 2,
// counted vmcnt (T4), swizzled staging (T2, zero-conflict verified R2),
// n-major XCD-chunked decode (T1), setprio (T5).  M assumed 2048 (nbm=16).
template <int OUT_BF16>
__global__ __launch_bounds__(256, 3) void gemm_cr(const bf16* __restrict__ A,
                                                  const bf16* __restrict__ BT,
                                                  void* __restrict__ Cout,
                                                  int N, int K) {
  extern __shared__ char smem[];
  constexpr int BUFB = 128 * 32 * 2 * 2;  // 16 KiB per K-tile buffer (A 8K + B 8K)
  const int t = threadIdx.x;
  const int lane = t & 63, w = t >> 6;
  const int l16 = lane & 15, lq = lane >> 4;

  const int nwg = gridDim.x;  // divisible by 8
  const int lin = ((int)blockIdx.x & 7) * (nwg >> 3) + ((int)blockIdx.x >> 3);
  const int m0 = (lin & 15) * 128;         // m-major inner (same XCD shares B panels)
  const int n0 = (lin >> 4) * 128;

  const int wrow = (w & 1) * 64;
  const int wcol = (w >> 1) * 64;

  // staging sources: pre-swizzled global (slot XOR), linear LDS dest
  const bf16* gA[2];
  const bf16* gB[2];
#pragma unroll
  for (int l = 0; l < 2; ++l) {
    const int row = (t >> 2) + l * 64;
    const int slot = (t & 3) ^ ((row >> 1) & 3);
    gA[l] = A + (size_t)(m0 + row) * K + slot * 8;
    gB[l] = BT + (size_t)(n0 + row) * K + slot * 8;
  }

  // swizzled fragment byte offsets
  int aoff[4], boff[4];
#pragma unroll
  for (int f = 0; f < 4; ++f) {
    const int ra = wrow + f * 16 + l16;
    aoff[f] = ra * 64 + ((lq ^ ((ra >> 1) & 3)) << 4);
    const int rb = wcol + f * 16 + l16;
    boff[f] = 8192 + rb * 64 + ((lq ^ ((rb >> 1) & 3)) << 4);
  }

  auto stage = [&](char* buf, int kt) {
    char* dst = buf + t * 16;
#pragma unroll
    for (int l = 0; l < 2; ++l) {
      async16(gA[l] + (size_t)kt * 32, dst + l * 4096);
      async16(gB[l] + (size_t)kt * 32, dst + 8192 + l * 4096);
    }
  };

  char* bufA = smem;
  char* bufB = smem + BUFB;
  char* bufC = smem + 2 * BUFB;

  f32x4 acc[4][4] = {};
  const int NT = K >> 5;

  stage(bufA, 0);
  stage(bufB, 1);

  for (int kt = 0; kt < NT; ++kt) {
    barrier_raw();  // all waves done reading the buffer bufC is about to overwrite
    if (kt + 2 < NT) {
      stage(bufC, kt + 2);
      VMCNT(8);  // wait tile kt landed; kt+1, kt+2 stay in flight
    } else if (kt + 1 < NT) {
      VMCNT(4);
    } else {
      VMCNT(0);
    }
    barrier_raw();  // all waves' stage(kt) landed

    bf16x8 bfrag[4];
#pragma unroll
    for (int fn = 0; fn < 4; ++fn) bfrag[fn] = *(const bf16x8*)(bufA + boff[fn]);
    __builtin_amdgcn_s_setprio(1);
#pragma unroll
    for (int fm = 0; fm < 4; ++fm) {
      bf16x8 af = *(const bf16x8*)(bufA + aoff[fm]);
#pragma unroll
      for (int fn = 0; fn < 4; ++fn) acc[fm][fn] = MFMA(af, bfrag[fn], acc[fm][fn]);
    }
    __builtin_amdgcn_s_setprio(0);

    char* tmp = bufA;  // rotate: A<-B (tile kt+1), B<-C (tile kt+2), C<-old A
    bufA = bufB;
    bufB = bufC;
    bufC = tmp;
  }

#pragma unroll
  for (int fm = 0; fm < 4; ++fm)
#pragma unroll
    for (int fn = 0; fn < 4; ++fn)
#pragma unroll
      for (int r = 0; r < 4; ++r) {
        const int row = m0 + wrow + fm * 16 + lq * 4 + r;
        const int col = n0 + wcol + fn * 16 + l16;
        if (OUT_BF16)
          ((bf16*)Cout)[(size_t)row * N + col] = (bf16)acc[fm][fn][r];
        else
          ((float*)Cout)[(size_t)row * N + col] = acc[fm][fn][r];
      }
}

// ---------------- RoPE + reshape: qkv -> Q[b][h][s][d] (scaled), K[b][kv][s][d], VT[b][kv][d][s] ----------------
__global__ __launch_bounds__(256) void rope_reshape(const bf16* __restrict__ qkv,
                                                    const float* __restrict__ cosp,
                                                    const float* __restrict__ sinp,
                                                    bf16* __restrict__ Qo,
                                                    bf16* __restrict__ Ko,
                                                    bf16* __restrict__ VTo) {
  const int row = blockIdx.x;          // b*SEQ + s
  const int b = row >> 10, s = row & 1023;
  const bf16* src = qkv + (size_t)row * QKV_N;
  for (int p = threadIdx.x; p < QKV_N / 2; p += 256) {
    const int col = p * 2;
    bf16x2 x = *(const bf16x2*)&src[col];
    const float x1 = (float)x.x, x2 = (float)x.y;
    if (col < 4096) {
      const int h = col >> 7, d = col & 127, i = (col & 127) >> 1;
      const float c = cosp[s * 64 + i], sn = sinp[s * 64 + i];
      bf16x2 o = {(bf16)((x1 * c - x2 * sn) * SCALE), (bf16)((x1 * sn + x2 * c) * SCALE)};
      *(bf16x2*)&Qo[((size_t)(b * NH + h) * SEQ + s) * DH + d] = o;
    } else if (col < 5120) {
      const int idx = col - 4096;
      const int kvh = idx >> 7, d = idx & 127, i = (idx & 127) >> 1;
      const float c = cosp[s * 64 + i], sn = sinp[s * 64 + i];
      bf16x2 o = {(bf16)(x1 * c - x2 * sn), (bf16)(x1 * sn + x2 * c)};
      *(bf16x2*)&Ko[((size_t)(b * NKV + kvh) * SEQ + s) * DH + d] = o;
    } else {
      const int idx = col - 5120;
      const int kvh = idx >> 7, d = idx & 127;
      bf16* vbase = VTo + ((size_t)(b * NKV + kvh) * DH + d) * SEQ + s;
      vbase[0] = x.x;
      vbase[SEQ] = x.y;
    }
  }
}

// ---------------- causal GQA flash attention, paired q-tiles ----------------
__global__ __launch_bounds__(256, 2) void flash_attn(const bf16* __restrict__ Q,
                                                     const bf16* __restrict__ K,
                                                     const bf16* __restrict__ VT,
                                                     bf16* __restrict__ O) {
  const int lane = threadIdx.x & 63, w = threadIdx.x >> 6;
  const int l16 = lane & 15, lq = lane >> 4;
  const int p = blockIdx.x * 4 + w;  // 0..2047
  const int b = p >> 10, h = (p >> 5) & 31, t = p & 31;
  const int kvh = h >> 2;  // G = 4

  const bf16* Qb = Q + (size_t)(b * NH + h) * SEQ * DH;
  const bf16* Kb = K + (size_t)(b * NKV + kvh) * SEQ * DH;
  const bf16* Vb = VT + (size_t)(b * NKV + kvh) * DH * SEQ;

  const int qrA = t * 16, qrB = (63 - t) * 16;
  const int nA = t / 4 + 1, nB = (63 - t) / 4 + 1;

  __shared__ bf16 plds[4][2][16][72];

  bf16x8 qfA[4], qfB[4];
#pragma unroll
  for (int kk = 0; kk < 4; ++kk) {
    qfA[kk] = *(const bf16x8*)&Qb[(size_t)(qrA + l16) * DH + kk * 32 + lq * 8];
    qfB[kk] = *(const bf16x8*)&Qb[(size_t)(qrB + l16) * DH + kk * 32 + lq * 8];
  }

  f32x4 accA[8] = {}, accB[8] = {};
  float mA[4], lA[4], mB[4], lB[4];
#pragma unroll
  for (int r = 0; r < 4; ++r) {
    mA[r] = mB[r] = -INFINITY;
    lA[r] = lB[r] = 0.f;
  }

  auto finish = [&](f32x4(&s)[4], float(&m)[4], float(&l)[4], f32x4(&acc)[8], int slot,
                    bool mask, int kv, int qr) {
    if (mask) {
#pragma unroll
      for (int nt = 0; nt < 4; ++nt)
#pragma unroll
        for (int r = 0; r < 4; ++r)
          if (kv * 64 + nt * 16 + l16 > qr + lq * 4 + r) s[nt][r] = -INFINITY;
    }
#pragma unroll
    for (int r = 0; r < 4; ++r) {
      float mx = fmaxf(fmaxf(s[0][r], s[1][r]), fmaxf(s[2][r], s[3][r]));
#pragma unroll
      for (int off = 1; off < 16; off <<= 1) mx = fmaxf(mx, __shfl_xor(mx, off));
      const float mn = fmaxf(m[r], mx);
      const float corr = __expf(m[r] - mn);
      m[r] = mn;
      float ps = 0.f;
#pragma unroll
      for (int nt = 0; nt < 4; ++nt) {
        const float pv = __expf(s[nt][r] - mn);
        s[nt][r] = pv;
        ps += pv;
      }
#pragma unroll
      for (int off = 1; off < 16; off <<= 1) ps += __shfl_xor(ps, off);
      l[r] = l[r] * corr + ps;
#pragma unroll
      for (int j = 0; j < 8; ++j) acc[j][r] *= corr;
    }
#pragma unroll
    for (int nt = 0; nt < 4; ++nt)
#pragma unroll
      for (int r = 0; r < 4; ++r)
        plds[w][slot][lq * 4 + r][nt * 16 + l16] = (bf16)s[nt][r];
  };

  int kv = 0;
  for (; kv < nA; ++kv) {
    f32x4 sA[4] = {}, sB[4] = {};
    const bf16* kbase = &Kb[(size_t)(kv * 64 + l16) * DH + lq * 8];
#pragma unroll
    for (int nt = 0; nt < 4; ++nt) {
      const bf16* kr = kbase + (size_t)nt * 16 * DH;
      bf16x8 k0 = *(const bf16x8*)kr;
      bf16x8 k1 = *(const bf16x8*)(kr + 32);
      bf16x8 k2 = *(const bf16x8*)(kr + 64);
      bf16x8 k3 = *(const bf16x8*)(kr + 96);
      sA[nt] = MFMA(qfA[0], k0, sA[nt]);
      sB[nt] = MFMA(qfB[0], k0, sB[nt]);
      sA[nt] = MFMA(qfA[1], k1, sA[nt]);
      sB[nt] = MFMA(qfB[1], k1, sB[nt]);
      sA[nt] = MFMA(qfA[2], k2, sA[nt]);
      sB[nt] = MFMA(qfB[2], k2, sB[nt]);
      sA[nt] = MFMA(qfA[3], k3, sA[nt]);
      sB[nt] = MFMA(qfB[3], k3, sB[nt]);
    }
    finish(sA, mA, lA, accA, 0, kv == nA - 1, kv, qrA);
    finish(sB, mB, lB, accB, 1, false, kv, qrB);
    bf16x8 pA0 = *(const bf16x8*)&plds[w][0][l16][lq * 8];
    bf16x8 pA1 = *(const bf16x8*)&plds[w][0][l16][32 + lq * 8];
    bf16x8 pB0 = *(const bf16x8*)&plds[w][1][l16][lq * 8];
    bf16x8 pB1 = *(const bf16x8*)&plds[w][1][l16][32 + lq * 8];
    const bf16* vbase = &Vb[(size_t)l16 * SEQ + kv * 64 + lq * 8];
#pragma unroll
    for (int j = 0; j < 8; ++j) {
      const bf16* vr = vbase + (size_t)j * 16 * SEQ;
      bf16x8 v0 = *(const bf16x8*)vr;
      bf16x8 v1 = *(const bf16x8*)(vr + 32);
      accA[j] = MFMA(pA0, v0, accA[j]);
      accB[j] = MFMA(pB0, v0, accB[j]);
      accA[j] = MFMA(pA1, v1, accA[j]);
      accB[j] = MFMA(pB1, v1, accB[j]);
    }
  }
  for (; kv < nB; ++kv) {
    f32x4 sB[4] = {};
    const bf16* kbase = &Kb[(size_t)(kv * 64 + l16) * DH + lq * 8];
#pragma unroll
    for (int nt = 0; nt < 4; ++nt) {
      const bf16* kr = kbase + (size_t)nt * 16 * DH;
      bf16x8 k0 = *(const bf16x8*)kr;
      bf16x8 k1 = *(const bf16x8*)(kr + 32);
      bf16x8 k2 = *(const bf16x8*)(kr + 64);
      bf16x8 k3 = *(const bf16x8*)(kr + 96);
      sB[nt] = MFMA(qfB[0], k0, sB[nt]);
      sB[nt] = MFMA(qfB[1], k1, sB[nt]);
      sB[nt] = MFMA(qfB[2], k2, sB[nt]);
      sB[nt] = MFMA(qfB[3], k3, sB[nt]);
    }
    finish(sB, mB, lB, accB, 1, kv == nB - 1, kv, qrB);
    bf16x8 pB0 = *(const bf16x8*)&plds[w][1][l16][lq * 8];
    bf16x8 pB1 = *(const bf16x8*)&plds[w][1][l16][32 + lq * 8];
    const bf16* vbase = &Vb[(size_t)l16 * SEQ + kv * 64 + lq * 8];
#pragma unroll
    for (int j = 0; j < 8; ++j) {
      const bf16* vr = vbase + (size_t)j * 16 * SEQ;
      bf16x8 v0 = *(const bf16x8*)vr;
      bf16x8 v1 = *(const bf16x8*)(vr + 32);
      accB[j] = MFMA(pB0, v0, accB[j]);
      accB[j] = MFMA(pB1, v1, accB[j]);
    }
  }

  auto wout = [&](f32x4(&acc)[8], float(&l)[4], int qr) {
#pragma unroll
    for (int r = 0; r < 4; ++r) {
      const float inv = 1.f / l[r];
      const size_t orow = ((size_t)b * SEQ + qr + lq * 4 + r) * HIDN + h * DH;
#pragma unroll
      for (int j = 0; j < 8; ++j) O[orow + j * 16 + l16] = (bf16)(acc[j][r] * inv);
    }
  };
  wout(accA, lA, qrA);
  wout(accB, lB, qrB);
}

extern "C" void kernel_launch(void* const* d_in, const int* in_sizes, int n_in,
                              void* d_out, int out_size, void* d_ws, size_t ws_size,
                              hipStream_t stream) {
  const float* hidden = (const float*)d_in[0];
  const float* cosp = (const float*)d_in[1];
  const float* sinp = (const float*)d_in[2];
  const float* wqkv = (const float*)d_in[3];
  const float* wo = (const float*)d_in[4];
  float* out = (float*)d_out;

  char* ws = (char*)d_ws;
  bf16* hiddenB = (bf16*)(ws);                 // 16,777,216   [2048][4096]
  bf16* wqkvT  = (bf16*)(ws + 16777216);       // 50,331,648   [6144][4096]
  bf16* woT    = (bf16*)(ws + 67108864);       // 33,554,432   [4096][4096]
  bf16* qkvB   = (bf16*)(ws + 100663296);      // 25,165,824   [2048][6144]
  bf16* Qb     = (bf16*)(ws + 125829120);      // 16,777,216   [2][32][1024][128]
  bf16* Kb     = (bf16*)(ws + 142606336);      //  4,194,304   [2][8][1024][128]
  bf16* VTb    = (bf16*)(ws + 146800640);      //  4,194,304   [2][8][128][1024]
  bf16* attnB  = hiddenB;                      // alias: hiddenB dead after gemm1

  cvt_f32_bf16<<<8192, 256, 0, stream>>>(hidden, hiddenB, 2097152);
  transpose_cvt<<<dim3(192, 128), 256, 0, stream>>>(wqkv, wqkvT, 4096, 6144);
  transpose_cvt<<<dim3(128, 128), 256, 0, stream>>>(wo, woT, 4096, 4096);
  gemm_cr<1><<<dim3(768), 256, 49152, stream>>>(hiddenB, wqkvT, qkvB, 6144, 4096);
  rope_reshape<<<2048, 256, 0, stream>>>(qkvB, cosp, sinp, Qb, Kb, VTb);
  flash_attn<<<dim3(512), 256, 0, stream>>>(Qb, Kb, VTb, attnB);
  gemm_cr<0><<<dim3(512), 256, 49152, stream>>>(attnB, woT, out, 4096, 4096);
}